// Round 4
// baseline (2192.921 us; speedup 1.0000x reference)
//
#include <hip/hip_runtime.h>
#include <math.h>

#define BT_TOTAL 4096
#define DD 768
#define TWOD 1536
#define M_MEM 8
#define NHID 16
#define NSY 512
#define K_ITER 8

__device__ __forceinline__ float sigmoidf_(float x) {
    return 1.0f / (1.0f + __expf(-x));
}

// ---------------------------------------------------------------------------
// init: state = broadcast(start_state); alpha = 0
// ---------------------------------------------------------------------------
__global__ __launch_bounds__(256)
void init_kernel(float* __restrict__ state, float* __restrict__ alpha,
                 const float* __restrict__ start_state) {
    int idx = blockIdx.x * 256 + threadIdx.x;
    const int nstate = BT_TOTAL * DD;
    if (idx < nstate) {
        state[idx] = start_state[idx % DD];
    } else {
        int a = idx - nstate;
        if (a < BT_TOTAL * NSY) alpha[a] = 0.0f;
    }
}

// ---------------------------------------------------------------------------
// wps[d][s] = W_proj[d][s] * rsqrt(beta[s]),  beta[s] = sum_{i=0..7} r^i
// ---------------------------------------------------------------------------
__global__ __launch_bounds__(256)
void scale_wproj_kernel(const float* __restrict__ wproj,
                        const float* __restrict__ decay,
                        float* __restrict__ wps) {
    int idx = blockIdx.x * 256 + threadIdx.x;   // < 768*512
    int s = idx & (NSY - 1);
    float dcl = fminf(fmaxf(decay[s], 0.0f), 15.0f);
    float r = __expf(-dcl);
    float beta = 1.0f, rp = r;
    #pragma unroll
    for (int i = 1; i < K_ITER; ++i) { beta += rp; rp *= r; }
    wps[idx] = wproj[idx] * rsqrtf(beta);
}

// ---------------------------------------------------------------------------
// Generic fp32 GEMM:  C[i][j] = (C0?C0[i][j]:0) + sum_k A[i*lda+k]*B[j*ldb+k]
// M,N multiples of 128; K multiple of 16. 256 threads, 8x8 per thread.
// ---------------------------------------------------------------------------
#define GBM 128
#define GBN 128
#define GBK 16

__global__ __launch_bounds__(256)
void gemm_abT(const float* __restrict__ A, int lda,
              const float* __restrict__ B, int ldb,
              const float* __restrict__ C0,
              float* __restrict__ C, int ldc, int K) {
    __shared__ float As[GBK][GBM + 4];
    __shared__ float Bs[GBK][GBN + 4];
    const int tid = threadIdx.x;
    const int tx = tid & 15, ty = tid >> 4;
    const int row0 = blockIdx.y * GBM;
    const int col0 = blockIdx.x * GBN;
    const int lr = tid >> 2;          // 0..63
    const int lk = (tid & 3) << 2;    // 0,4,8,12

    float acc[8][8];
    #pragma unroll
    for (int i = 0; i < 8; ++i)
        #pragma unroll
        for (int j = 0; j < 8; ++j) acc[i][j] = 0.0f;

    const float* Ap  = A + (size_t)(row0 + lr) * lda + lk;
    const float* Ap2 = A + (size_t)(row0 + lr + 64) * lda + lk;
    const float* Bp  = B + (size_t)(col0 + lr) * ldb + lk;
    const float* Bp2 = B + (size_t)(col0 + lr + 64) * ldb + lk;

    for (int kt = 0; kt < K; kt += GBK) {
        float4 av0 = *(const float4*)(Ap  + kt);
        float4 av1 = *(const float4*)(Ap2 + kt);
        float4 bv0 = *(const float4*)(Bp  + kt);
        float4 bv1 = *(const float4*)(Bp2 + kt);
        __syncthreads();
        As[lk+0][lr] = av0.x; As[lk+1][lr] = av0.y; As[lk+2][lr] = av0.z; As[lk+3][lr] = av0.w;
        As[lk+0][lr+64] = av1.x; As[lk+1][lr+64] = av1.y; As[lk+2][lr+64] = av1.z; As[lk+3][lr+64] = av1.w;
        Bs[lk+0][lr] = bv0.x; Bs[lk+1][lr] = bv0.y; Bs[lk+2][lr] = bv0.z; Bs[lk+3][lr] = bv0.w;
        Bs[lk+0][lr+64] = bv1.x; Bs[lk+1][lr+64] = bv1.y; Bs[lk+2][lr+64] = bv1.z; Bs[lk+3][lr+64] = bv1.w;
        __syncthreads();
        #pragma unroll
        for (int kk = 0; kk < GBK; ++kk) {
            float a[8], b[8];
            *(float4*)&a[0] = *(const float4*)&As[kk][ty * 8];
            *(float4*)&a[4] = *(const float4*)&As[kk][ty * 8 + 4];
            *(float4*)&b[0] = *(const float4*)&Bs[kk][tx * 8];
            *(float4*)&b[4] = *(const float4*)&Bs[kk][tx * 8 + 4];
            #pragma unroll
            for (int i = 0; i < 8; ++i)
                #pragma unroll
                for (int j = 0; j < 8; ++j)
                    acc[i][j] = fmaf(a[i], b[j], acc[i][j]);
        }
    }

    #pragma unroll
    for (int i = 0; i < 8; ++i) {
        size_t roff = (size_t)(row0 + ty * 8 + i) * ldc + col0 + tx * 8;
        float o[8];
        #pragma unroll
        for (int j = 0; j < 8; ++j) o[j] = acc[i][j];
        if (C0) {
            #pragma unroll
            for (int j = 0; j < 8; ++j) o[j] += C0[roff + j];
        }
        *(float4*)(C + roff)     = *(const float4*)&o[0];
        *(float4*)(C + roff + 4) = *(const float4*)&o[4];
    }
}

// ---------------------------------------------------------------------------
// GLU + LayerNorm, one wave per row. act row: 1536; out: ns_hist[k] row: 768
// ---------------------------------------------------------------------------
__global__ __launch_bounds__(256)
void glu_ln_kernel(const float* __restrict__ act,
                   const float* __restrict__ ln_g, const float* __restrict__ ln_b,
                   float* __restrict__ ns_out) {
    int wave = threadIdx.x >> 6;
    int lane = threadIdx.x & 63;
    int row = blockIdx.x * 4 + wave;
    const float* arow = act + (size_t)row * TWOD;
    float g[12];
    float s = 0.0f, ss = 0.0f;
    #pragma unroll
    for (int q = 0; q < 12; ++q) {
        int c = lane + q * 64;
        float a = arow[c];
        float b = arow[c + DD];
        float v = a * sigmoidf_(b);
        g[q] = v; s += v; ss += v * v;
    }
    #pragma unroll
    for (int off = 32; off; off >>= 1) {
        s  += __shfl_xor(s, off);
        ss += __shfl_xor(ss, off);
    }
    float mu  = s * (1.0f / 768.0f);
    float var = ss * (1.0f / 768.0f) - mu * mu;
    float rstd = rsqrtf(var + 1e-5f);
    float* orow = ns_out + (size_t)row * DD;
    #pragma unroll
    for (int q = 0; q < 12; ++q) {
        int c = lane + q * 64;
        orow[c] = (g[q] - mu) * rstd * ln_g[c] + ln_b[c];
    }
}

// ---------------------------------------------------------------------------
// NLM: per-neuron 2-layer GLU MLP over trace window. Chunked weights in LDS.
// grid: (768/NC, 4096/RT); block 256.
// ---------------------------------------------------------------------------
#define NC 32
#define RT 32

__global__ __launch_bounds__(256)
void nlm_kernel(const float* __restrict__ ns_hist, const float* __restrict__ st,
                const float* __restrict__ w1, const float* __restrict__ b1,
                const float* __restrict__ w2, const float* __restrict__ b2,
                float* __restrict__ state, int k) {
    __shared__ float w1s[M_MEM][32][NC];   // 32 KB
    __shared__ float w2s[NHID][2][NC];     // 4 KB
    __shared__ float b1s[NC][33];
    __shared__ float b2s[NC][3];
    __shared__ float sts[NC][9];
    const int tid = threadIdx.x;
    const int n0 = blockIdx.x * NC;
    const int r0 = blockIdx.y * RT;

    for (int idx = tid; idx < M_MEM * 32 * NC; idx += 256) {
        int mo = idx / NC, nl = idx % NC;
        ((float*)w1s)[idx] = w1[(size_t)mo * DD + n0 + nl];
    }
    for (int idx = tid; idx < NHID * 2 * NC; idx += 256) {
        int mo = idx / NC, nl = idx % NC;
        ((float*)w2s)[idx] = w2[(size_t)mo * DD + n0 + nl];
    }
    for (int idx = tid; idx < NC * 32; idx += 256) {
        int nl = idx >> 5, o = idx & 31;
        b1s[nl][o] = b1[(size_t)(n0 + nl) * 32 + o];
    }
    if (tid < NC * 2) { int nl = tid >> 1, o = tid & 1; b2s[nl][o] = b2[(size_t)(n0 + nl) * 2 + o]; }
    if (tid < NC * 8) { int nl = tid >> 3, m = tid & 7; sts[nl][m] = st[(size_t)(n0 + nl) * 8 + m]; }
    __syncthreads();

    const int nl = tid & (NC - 1);
    const int n = n0 + nl;
    const int rbase = r0 + (tid >> 5);   // 8 row groups

    #pragma unroll
    for (int ri = 0; ri < 4; ++ri) {
        int row = rbase + ri * 8;
        float t[M_MEM];
        #pragma unroll
        for (int m = 0; m < M_MEM; ++m) {
            if (m < 7 - k)
                t[m] = sts[nl][m + k + 1];
            else
                t[m] = ns_hist[(size_t)(m - 7 + k) * (BT_TOTAL * DD) + (size_t)row * DD + n];
        }
        float h[NHID];
        #pragma unroll
        for (int o = 0; o < NHID; ++o) {
            float pa = b1s[nl][o], pb = b1s[nl][o + 16];
            #pragma unroll
            for (int m = 0; m < M_MEM; ++m) {
                pa = fmaf(t[m], w1s[m][o][nl], pa);
                pb = fmaf(t[m], w1s[m][o + 16][nl], pb);
            }
            h[o] = pa * sigmoidf_(pb);
        }
        float p0 = b2s[nl][0], p1 = b2s[nl][1];
        #pragma unroll
        for (int m = 0; m < NHID; ++m) {
            p0 = fmaf(h[m], w2s[m][0][nl], p0);
            p1 = fmaf(h[m], w2s[m][1][nl], p1);
        }
        state[(size_t)row * DD + n] = p0 * sigmoidf_(p1);
    }
}

// ---------------------------------------------------------------------------
// pp + alpha update. One wave per row.
// ---------------------------------------------------------------------------
__global__ __launch_bounds__(256)
void pp_kernel(const float* __restrict__ state, const float* __restrict__ decay,
               const int* __restrict__ sl, const int* __restrict__ sr,
               float* __restrict__ alpha) {
    __shared__ float srow[4][DD];
    int wave = threadIdx.x >> 6, lane = threadIdx.x & 63;
    int row = blockIdx.x * 4 + wave;
    const float* sp = state + (size_t)row * DD;
    #pragma unroll
    for (int q = 0; q < 12; ++q) srow[wave][lane + q * 64] = sp[lane + q * 64];
    __syncthreads();
    float* arow = alpha + (size_t)row * NSY;
    #pragma unroll
    for (int q = 0; q < 8; ++q) {
        int s = lane + q * 64;
        float dcl = fminf(fmaxf(decay[s], 0.0f), 15.0f);
        float r = __expf(-dcl);
        float pp = srow[wave][sl[s]] * srow[wave][sr[s]];
        arow[s] = r * arow[s] + pp;
    }
}

// ---------------------------------------------------------------------------
extern "C" void kernel_launch(void* const* d_in, const int* in_sizes, int n_in,
                              void* d_out, int out_size, void* d_ws, size_t ws_size,
                              hipStream_t stream) {
    const float* x        = (const float*)d_in[0];
    const float* W_syn    = (const float*)d_in[1];
    const float* ln_g     = (const float*)d_in[2];
    const float* ln_b     = (const float*)d_in[3];
    const float* w1       = (const float*)d_in[4];
    const float* b1       = (const float*)d_in[5];
    const float* w2       = (const float*)d_in[6];
    const float* b2       = (const float*)d_in[7];
    const float* start_st = (const float*)d_in[8];
    const float* start_tr = (const float*)d_in[9];
    const float* decay    = (const float*)d_in[10];
    const float* W_proj   = (const float*)d_in[11];
    const int*   sl       = (const int*)d_in[12];
    const int*   sr       = (const int*)d_in[13];
    float* out = (float*)d_out;

    float* ws    = (float*)d_ws;
    float* xpre  = ws;                                   // 4096*1536
    float* act   = xpre  + (size_t)BT_TOTAL * TWOD;      // 4096*1536
    float* state = act   + (size_t)BT_TOTAL * TWOD;      // 4096*768
    float* nsh   = state + (size_t)BT_TOTAL * DD;        // 8*4096*768
    float* alpha = nsh   + (size_t)K_ITER * BT_TOTAL * DD; // 4096*512
    float* wps   = alpha + (size_t)BT_TOTAL * NSY;       // 768*512

    // init state + alpha
    {
        int total = BT_TOTAL * (DD + NSY);
        init_kernel<<<(total + 255) / 256, 256, 0, stream>>>(state, alpha, start_st);
    }
    // scaled W_proj
    scale_wproj_kernel<<<(DD * NSY) / 256, 256, 0, stream>>>(W_proj, decay, wps);

    // xpre = x @ W_x^T
    {
        dim3 g(TWOD / GBN, BT_TOTAL / GBM);
        gemm_abT<<<g, 256, 0, stream>>>(x, DD, W_syn, TWOD, nullptr, xpre, TWOD, DD);
    }

    for (int k = 0; k < K_ITER; ++k) {
        // act = xpre + state @ W_s^T
        dim3 g(TWOD / GBN, BT_TOTAL / GBM);
        gemm_abT<<<g, 256, 0, stream>>>(state, DD, W_syn + DD, TWOD, xpre, act, TWOD, DD);
        // GLU + LN -> ns_hist[k]
        glu_ln_kernel<<<BT_TOTAL / 4, 256, 0, stream>>>(act, ln_g, ln_b,
                                                        nsh + (size_t)k * BT_TOTAL * DD);
        // NLM -> state
        dim3 gn(DD / NC, BT_TOTAL / RT);
        nlm_kernel<<<gn, 256, 0, stream>>>(nsh, start_tr, w1, b1, w2, b2, state, k);
        // pp + alpha
        pp_kernel<<<BT_TOTAL / 4, 256, 0, stream>>>(state, decay, sl, sr, alpha);
    }

    // out = alpha @ wps^T
    {
        dim3 g(DD / GBN, BT_TOTAL / GBM);
        gemm_abT<<<g, 256, 0, stream>>>(alpha, NSY, wps, NSY, nullptr, out, DD, NSY);
    }
}

// Round 6
// 1292.644 us; speedup vs baseline: 1.6965x; 1.6965x over previous
//
#include <hip/hip_runtime.h>
#include <math.h>

#define BT_TOTAL 4096
#define DD 768
#define TWOD 1536
#define M_MEM 8
#define NHID 16
#define NSY 512
#define K_ITER 8

typedef unsigned short u16;
typedef __attribute__((ext_vector_type(8))) __bf16 bf16x8;
typedef __attribute__((ext_vector_type(4))) float f32x4;

__device__ __forceinline__ float sigmoidf_(float x) {
    return 1.0f / (1.0f + __expf(-x));
}

__device__ __forceinline__ u16 f2bf(float f) {
    unsigned int u = __float_as_uint(f);
    unsigned int r = (u + 0x7FFFu + ((u >> 16) & 1u)) >> 16;
    return (u16)r;
}
__device__ __forceinline__ float bf2f(u16 h) {
    return __uint_as_float(((unsigned int)h) << 16);
}

__device__ __forceinline__ void gload_lds16(const void* g, void* l) {
    __builtin_amdgcn_global_load_lds(
        (const __attribute__((address_space(1))) unsigned int*)g,
        (__attribute__((address_space(3))) unsigned int*)l,
        16, 0, 0);
}

// ---------------------------------------------------------------------------
// init: state hi/lo = split(start_state); alpha = 0
// ---------------------------------------------------------------------------
__global__ __launch_bounds__(256)
void init_kernel(u16* __restrict__ shi, u16* __restrict__ slo,
                 float* __restrict__ alpha, const float* __restrict__ start_state) {
    int idx = blockIdx.x * 256 + threadIdx.x;
    const int nstate = BT_TOTAL * DD;
    if (idx < nstate) {
        float a = start_state[idx % DD];
        u16 h = f2bf(a);
        shi[idx] = h;
        slo[idx] = f2bf(a - bf2f(h));
    } else {
        int a = idx - nstate;
        if (a < BT_TOTAL * NSY) alpha[a] = 0.0f;
    }
}

// ---------------------------------------------------------------------------
// split W_syn halves: wx = W[:, :768], ws = W[:, 768:]  (each 1536x768)
// ---------------------------------------------------------------------------
__global__ __launch_bounds__(256)
void split_w_kernel(const float* __restrict__ W,
                    u16* __restrict__ wxhi, u16* __restrict__ wxlo,
                    u16* __restrict__ wshi, u16* __restrict__ wslo) {
    int idx = blockIdx.x * 256 + threadIdx.x;   // < 1536*768
    int j = idx / DD, k = idx % DD;
    float a = W[(size_t)j * TWOD + k];
    float b = W[(size_t)j * TWOD + DD + k];
    u16 ha = f2bf(a); wxhi[idx] = ha; wxlo[idx] = f2bf(a - bf2f(ha));
    u16 hb = f2bf(b); wshi[idx] = hb; wslo[idx] = f2bf(b - bf2f(hb));
}

// ---------------------------------------------------------------------------
// split x -> xhi, xlo
// ---------------------------------------------------------------------------
__global__ __launch_bounds__(256)
void split_x_kernel(const float* __restrict__ x,
                    u16* __restrict__ xhi, u16* __restrict__ xlo) {
    int idx = blockIdx.x * 256 + threadIdx.x;   // < 4096*768
    float a = x[idx];
    u16 h = f2bf(a);
    xhi[idx] = h;
    xlo[idx] = f2bf(a - bf2f(h));
}

// ---------------------------------------------------------------------------
// wps[d][s] = W_proj[d][s] * rsqrt(beta[s]),  beta[s] = sum_{i=0..7} r^i
// ---------------------------------------------------------------------------
__global__ __launch_bounds__(256)
void scale_wproj_kernel(const float* __restrict__ wproj,
                        const float* __restrict__ decay,
                        float* __restrict__ wps) {
    int idx = blockIdx.x * 256 + threadIdx.x;   // < 768*512
    int s = idx & (NSY - 1);
    float dcl = fminf(fmaxf(decay[s], 0.0f), 15.0f);
    float r = __expf(-dcl);
    float beta = 1.0f, rp = r;
    #pragma unroll
    for (int i = 1; i < K_ITER; ++i) { beta += rp; rp *= r; }
    wps[idx] = wproj[idx] * rsqrtf(beta);
}

// ---------------------------------------------------------------------------
// Split-bf16 MFMA GEMM: C(M x N) = (Ahi+Alo)(4096x768) @ (Bhi+Blo)^T(N x 768)
// + optional C0. 128x128 tile, BK=64, 4 waves (2x2), 16x16x32 bf16 MFMA,
// 3-term split (hi*hi + hi*lo + lo*hi). XOR-swizzled LDS (slot ^ (row&7)),
// pre-swizzled global source (rule #21), global_load_lds width 16.
// ---------------------------------------------------------------------------
#define TM 128
#define TN 128
#define TK 64

__global__ __launch_bounds__(256)
void gemm_mfma_split(const u16* __restrict__ Ahi, const u16* __restrict__ Alo,
                     const u16* __restrict__ Bhi, const u16* __restrict__ Blo,
                     const float* __restrict__ C0,
                     float* __restrict__ C, int ldc) {
    __shared__ u16 sAh[TM * TK];
    __shared__ u16 sAl[TM * TK];
    __shared__ u16 sBh[TN * TK];
    __shared__ u16 sBl[TN * TK];
    const int tid  = threadIdx.x;
    const int w    = tid >> 6;
    const int lane = tid & 63;
    const int row0 = blockIdx.y * TM;
    const int col0 = blockIdx.x * TN;
    const int wr = (w >> 1) * 64;      // wave row offset in tile
    const int wc = (w & 1) * 64;       // wave col offset in tile

    const f32x4 zero = {0.f, 0.f, 0.f, 0.f};
    f32x4 acc[4][4];
    #pragma unroll
    for (int i = 0; i < 4; ++i)
        #pragma unroll
        for (int j = 0; j < 4; ++j) acc[i][j] = zero;

    const int lr = lane >> 3;   // row within 8-row staging group
    const int ls = lane & 7;    // 16B slot within 128B row

    for (int kt = 0; kt < DD; kt += TK) {
        __syncthreads();
        #pragma unroll
        for (int g = 0; g < 4; ++g) {
            int r  = w * 32 + g * 8 + lr;          // tile row 0..127
            int ss = ls ^ (r & 7);                 // pre-swizzled slot
            size_t goffA = (size_t)(row0 + r) * DD + kt + ss * 8;
            size_t goffB = (size_t)(col0 + r) * DD + kt + ss * 8;
            int lo = (w * 32 + g * 8) * TK;        // element offset in LDS
            gload_lds16(Ahi + goffA, &sAh[lo]);
            gload_lds16(Alo + goffA, &sAl[lo]);
            gload_lds16(Bhi + goffB, &sBh[lo]);
            gload_lds16(Blo + goffB, &sBl[lo]);
        }
        __syncthreads();
        #pragma unroll
        for (int ks = 0; ks < 2; ++ks) {
            bf16x8 ah[4], al[4], bh[4], bl[4];
            #pragma unroll
            for (int f = 0; f < 4; ++f) {
                int ra = wr + f * 16 + (lane & 15);
                int sa = (ks * 4 + (lane >> 4)) ^ (ra & 7);
                ah[f] = *(const bf16x8*)(const void*)(sAh + ra * TK + sa * 8);
                al[f] = *(const bf16x8*)(const void*)(sAl + ra * TK + sa * 8);
                int rb = wc + f * 16 + (lane & 15);
                int sb = (ks * 4 + (lane >> 4)) ^ (rb & 7);
                bh[f] = *(const bf16x8*)(const void*)(sBh + rb * TK + sb * 8);
                bl[f] = *(const bf16x8*)(const void*)(sBl + rb * TK + sb * 8);
            }
            #pragma unroll
            for (int i = 0; i < 4; ++i)
                #pragma unroll
                for (int j = 0; j < 4; ++j) {
                    acc[i][j] = __builtin_amdgcn_mfma_f32_16x16x32_bf16(ah[i], bh[j], acc[i][j], 0, 0, 0);
                    acc[i][j] = __builtin_amdgcn_mfma_f32_16x16x32_bf16(ah[i], bl[j], acc[i][j], 0, 0, 0);
                    acc[i][j] = __builtin_amdgcn_mfma_f32_16x16x32_bf16(al[i], bh[j], acc[i][j], 0, 0, 0);
                }
        }
    }

    // epilogue: C/D layout col=lane&15, row=(lane>>4)*4+q  [m89-verified]
    const int cc = lane & 15;
    const int rr = (lane >> 4) * 4;
    #pragma unroll
    for (int i = 0; i < 4; ++i) {
        #pragma unroll
        for (int j = 0; j < 4; ++j) {
            int gr = row0 + wr + i * 16 + rr;
            int gc = col0 + wc + j * 16 + cc;
            #pragma unroll
            for (int q = 0; q < 4; ++q) {
                size_t off = (size_t)(gr + q) * ldc + gc;
                float v = acc[i][j][q];
                if (C0) v += C0[off];
                C[off] = v;
            }
        }
    }
}

// ---------------------------------------------------------------------------
// Generic fp32 GEMM (kept for final projection):
// C[i][j] = sum_k A[i*lda+k]*B[j*ldb+k]
// ---------------------------------------------------------------------------
#define GBM 128
#define GBN 128
#define GBK 16

__global__ __launch_bounds__(256)
void gemm_abT(const float* __restrict__ A, int lda,
              const float* __restrict__ B, int ldb,
              const float* __restrict__ C0,
              float* __restrict__ C, int ldc, int K) {
    __shared__ float As[GBK][GBM + 4];
    __shared__ float Bs[GBK][GBN + 4];
    const int tid = threadIdx.x;
    const int tx = tid & 15, ty = tid >> 4;
    const int row0 = blockIdx.y * GBM;
    const int col0 = blockIdx.x * GBN;
    const int lr = tid >> 2;
    const int lk = (tid & 3) << 2;

    float acc[8][8];
    #pragma unroll
    for (int i = 0; i < 8; ++i)
        #pragma unroll
        for (int j = 0; j < 8; ++j) acc[i][j] = 0.0f;

    const float* Ap  = A + (size_t)(row0 + lr) * lda + lk;
    const float* Ap2 = A + (size_t)(row0 + lr + 64) * lda + lk;
    const float* Bp  = B + (size_t)(col0 + lr) * ldb + lk;
    const float* Bp2 = B + (size_t)(col0 + lr + 64) * ldb + lk;

    for (int kt = 0; kt < K; kt += GBK) {
        float4 av0 = *(const float4*)(Ap  + kt);
        float4 av1 = *(const float4*)(Ap2 + kt);
        float4 bv0 = *(const float4*)(Bp  + kt);
        float4 bv1 = *(const float4*)(Bp2 + kt);
        __syncthreads();
        As[lk+0][lr] = av0.x; As[lk+1][lr] = av0.y; As[lk+2][lr] = av0.z; As[lk+3][lr] = av0.w;
        As[lk+0][lr+64] = av1.x; As[lk+1][lr+64] = av1.y; As[lk+2][lr+64] = av1.z; As[lk+3][lr+64] = av1.w;
        Bs[lk+0][lr] = bv0.x; Bs[lk+1][lr] = bv0.y; Bs[lk+2][lr] = bv0.z; Bs[lk+3][lr] = bv0.w;
        Bs[lk+0][lr+64] = bv1.x; Bs[lk+1][lr+64] = bv1.y; Bs[lk+2][lr+64] = bv1.z; Bs[lk+3][lr+64] = bv1.w;
        __syncthreads();
        #pragma unroll
        for (int kk = 0; kk < GBK; ++kk) {
            float a[8], b[8];
            *(float4*)&a[0] = *(const float4*)&As[kk][ty * 8];
            *(float4*)&a[4] = *(const float4*)&As[kk][ty * 8 + 4];
            *(float4*)&b[0] = *(const float4*)&Bs[kk][tx * 8];
            *(float4*)&b[4] = *(const float4*)&Bs[kk][tx * 8 + 4];
            #pragma unroll
            for (int i = 0; i < 8; ++i)
                #pragma unroll
                for (int j = 0; j < 8; ++j)
                    acc[i][j] = fmaf(a[i], b[j], acc[i][j]);
        }
    }

    #pragma unroll
    for (int i = 0; i < 8; ++i) {
        size_t roff = (size_t)(row0 + ty * 8 + i) * ldc + col0 + tx * 8;
        float o[8];
        #pragma unroll
        for (int j = 0; j < 8; ++j) o[j] = acc[i][j];
        if (C0) {
            #pragma unroll
            for (int j = 0; j < 8; ++j) o[j] += C0[roff + j];
        }
        *(float4*)(C + roff)     = *(const float4*)&o[0];
        *(float4*)(C + roff + 4) = *(const float4*)&o[4];
    }
}

// ---------------------------------------------------------------------------
// GLU + LayerNorm, one wave per row. act row: 1536; out: ns_hist[k] row: 768
// ---------------------------------------------------------------------------
__global__ __launch_bounds__(256)
void glu_ln_kernel(const float* __restrict__ act,
                   const float* __restrict__ ln_g, const float* __restrict__ ln_b,
                   float* __restrict__ ns_out) {
    int wave = threadIdx.x >> 6;
    int lane = threadIdx.x & 63;
    int row = blockIdx.x * 4 + wave;
    const float* arow = act + (size_t)row * TWOD;
    float g[12];
    float s = 0.0f, ss = 0.0f;
    #pragma unroll
    for (int q = 0; q < 12; ++q) {
        int c = lane + q * 64;
        float a = arow[c];
        float b = arow[c + DD];
        float v = a * sigmoidf_(b);
        g[q] = v; s += v; ss += v * v;
    }
    #pragma unroll
    for (int off = 32; off; off >>= 1) {
        s  += __shfl_xor(s, off);
        ss += __shfl_xor(ss, off);
    }
    float mu  = s * (1.0f / 768.0f);
    float var = ss * (1.0f / 768.0f) - mu * mu;
    float rstd = rsqrtf(var + 1e-5f);
    float* orow = ns_out + (size_t)row * DD;
    #pragma unroll
    for (int q = 0; q < 12; ++q) {
        int c = lane + q * 64;
        orow[c] = (g[q] - mu) * rstd * ln_g[c] + ln_b[c];
    }
}

// ---------------------------------------------------------------------------
// NLM: per-neuron 2-layer GLU MLP. Output written as split bf16 hi/lo.
// ---------------------------------------------------------------------------
#define NC 32
#define RT 32

__global__ __launch_bounds__(256)
void nlm_kernel(const float* __restrict__ ns_hist, const float* __restrict__ st,
                const float* __restrict__ w1, const float* __restrict__ b1,
                const float* __restrict__ w2, const float* __restrict__ b2,
                u16* __restrict__ shi, u16* __restrict__ slo, int k) {
    __shared__ float w1s[M_MEM][32][NC];
    __shared__ float w2s[NHID][2][NC];
    __shared__ float b1s[NC][33];
    __shared__ float b2s[NC][3];
    __shared__ float sts[NC][9];
    const int tid = threadIdx.x;
    const int n0 = blockIdx.x * NC;
    const int r0 = blockIdx.y * RT;

    for (int idx = tid; idx < M_MEM * 32 * NC; idx += 256) {
        int mo = idx / NC, nl = idx % NC;
        ((float*)w1s)[idx] = w1[(size_t)mo * DD + n0 + nl];
    }
    for (int idx = tid; idx < NHID * 2 * NC; idx += 256) {
        int mo = idx / NC, nl = idx % NC;
        ((float*)w2s)[idx] = w2[(size_t)mo * DD + n0 + nl];
    }
    for (int idx = tid; idx < NC * 32; idx += 256) {
        int nl = idx >> 5, o = idx & 31;
        b1s[nl][o] = b1[(size_t)(n0 + nl) * 32 + o];
    }
    if (tid < NC * 2) { int nl = tid >> 1, o = tid & 1; b2s[nl][o] = b2[(size_t)(n0 + nl) * 2 + o]; }
    if (tid < NC * 8) { int nl = tid >> 3, m = tid & 7; sts[nl][m] = st[(size_t)(n0 + nl) * 8 + m]; }
    __syncthreads();

    const int nl = tid & (NC - 1);
    const int n = n0 + nl;
    const int rbase = r0 + (tid >> 5);

    #pragma unroll
    for (int ri = 0; ri < 4; ++ri) {
        int row = rbase + ri * 8;
        float t[M_MEM];
        #pragma unroll
        for (int m = 0; m < M_MEM; ++m) {
            if (m < 7 - k)
                t[m] = sts[nl][m + k + 1];
            else
                t[m] = ns_hist[(size_t)(m - 7 + k) * (BT_TOTAL * DD) + (size_t)row * DD + n];
        }
        float h[NHID];
        #pragma unroll
        for (int o = 0; o < NHID; ++o) {
            float pa = b1s[nl][o], pb = b1s[nl][o + 16];
            #pragma unroll
            for (int m = 0; m < M_MEM; ++m) {
                pa = fmaf(t[m], w1s[m][o][nl], pa);
                pb = fmaf(t[m], w1s[m][o + 16][nl], pb);
            }
            h[o] = pa * sigmoidf_(pb);
        }
        float p0 = b2s[nl][0], p1 = b2s[nl][1];
        #pragma unroll
        for (int m = 0; m < NHID; ++m) {
            p0 = fmaf(h[m], w2s[m][0][nl], p0);
            p1 = fmaf(h[m], w2s[m][1][nl], p1);
        }
        float v = p0 * sigmoidf_(p1);
        size_t off = (size_t)row * DD + n;
        u16 hv = f2bf(v);
        shi[off] = hv;
        slo[off] = f2bf(v - bf2f(hv));
    }
}

// ---------------------------------------------------------------------------
// pp + alpha update. One wave per row. State reconstructed from hi+lo.
// ---------------------------------------------------------------------------
__global__ __launch_bounds__(256)
void pp_kernel(const u16* __restrict__ shi, const u16* __restrict__ slo,
               const float* __restrict__ decay,
               const int* __restrict__ sl, const int* __restrict__ sr,
               float* __restrict__ alpha) {
    __shared__ float srow[4][DD];
    int wave = threadIdx.x >> 6, lane = threadIdx.x & 63;
    int row = blockIdx.x * 4 + wave;
    size_t base = (size_t)row * DD;
    #pragma unroll
    for (int q = 0; q < 12; ++q) {
        int c = lane + q * 64;
        srow[wave][c] = bf2f(shi[base + c]) + bf2f(slo[base + c]);
    }
    __syncthreads();
    float* arow = alpha + (size_t)row * NSY;
    #pragma unroll
    for (int q = 0; q < 8; ++q) {
        int s = lane + q * 64;
        float dcl = fminf(fmaxf(decay[s], 0.0f), 15.0f);
        float r = __expf(-dcl);
        float pp = srow[wave][sl[s]] * srow[wave][sr[s]];
        arow[s] = r * arow[s] + pp;
    }
}

// ---------------------------------------------------------------------------
extern "C" void kernel_launch(void* const* d_in, const int* in_sizes, int n_in,
                              void* d_out, int out_size, void* d_ws, size_t ws_size,
                              hipStream_t stream) {
    const float* x        = (const float*)d_in[0];
    const float* W_syn    = (const float*)d_in[1];
    const float* ln_g     = (const float*)d_in[2];
    const float* ln_b     = (const float*)d_in[3];
    const float* w1       = (const float*)d_in[4];
    const float* b1       = (const float*)d_in[5];
    const float* w2       = (const float*)d_in[6];
    const float* b2       = (const float*)d_in[7];
    const float* start_st = (const float*)d_in[8];
    const float* start_tr = (const float*)d_in[9];
    const float* decay    = (const float*)d_in[10];
    const float* W_proj   = (const float*)d_in[11];
    const int*   sl       = (const int*)d_in[12];
    const int*   sr       = (const int*)d_in[13];
    float* out = (float*)d_out;

    // fp32 region
    float* ws    = (float*)d_ws;
    float* xpre  = ws;                                     // 4096*1536
    float* act   = xpre  + (size_t)BT_TOTAL * TWOD;        // 4096*1536
    float* nsh   = act   + (size_t)BT_TOTAL * TWOD;        // 8*4096*768
    float* alpha = nsh   + (size_t)K_ITER * BT_TOTAL * DD; // 4096*512
    float* wps   = alpha + (size_t)BT_TOTAL * NSY;         // 768*512
    // u16 region (after floats; all offsets 16B-aligned)
    u16* u16base = (u16*)(wps + (size_t)DD * NSY);
    u16* xhi  = u16base;                                   // 4096*768
    u16* xlo  = xhi  + (size_t)BT_TOTAL * DD;
    u16* shi  = xlo  + (size_t)BT_TOTAL * DD;
    u16* slo  = shi  + (size_t)BT_TOTAL * DD;
    u16* wxhi = slo  + (size_t)BT_TOTAL * DD;              // 1536*768
    u16* wxlo = wxhi + (size_t)TWOD * DD;
    u16* wshi = wxlo + (size_t)TWOD * DD;
    u16* wslo = wshi + (size_t)TWOD * DD;

    {
        int total = BT_TOTAL * (DD + NSY);
        init_kernel<<<(total + 255) / 256, 256, 0, stream>>>(shi, slo, alpha, start_st);
    }
    split_w_kernel<<<(TWOD * DD) / 256, 256, 0, stream>>>(W_syn, wxhi, wxlo, wshi, wslo);
    split_x_kernel<<<(BT_TOTAL * DD) / 256, 256, 0, stream>>>(x, xhi, xlo);
    scale_wproj_kernel<<<(DD * NSY) / 256, 256, 0, stream>>>(W_proj, decay, wps);

    // xpre = x @ W_x^T  (split-bf16 MFMA)
    {
        dim3 g(TWOD / TN, BT_TOTAL / TM);
        gemm_mfma_split<<<g, 256, 0, stream>>>(xhi, xlo, wxhi, wxlo, nullptr, xpre, TWOD);
    }

    for (int k = 0; k < K_ITER; ++k) {
        dim3 g(TWOD / TN, BT_TOTAL / TM);
        gemm_mfma_split<<<g, 256, 0, stream>>>(shi, slo, wshi, wslo, xpre, act, TWOD);
        glu_ln_kernel<<<BT_TOTAL / 4, 256, 0, stream>>>(act, ln_g, ln_b,
                                                        nsh + (size_t)k * BT_TOTAL * DD);
        dim3 gn(DD / NC, BT_TOTAL / RT);
        nlm_kernel<<<gn, 256, 0, stream>>>(nsh, start_tr, w1, b1, w2, b2, shi, slo, k);
        pp_kernel<<<BT_TOTAL / 4, 256, 0, stream>>>(shi, slo, decay, sl, sr, alpha);
    }

    // out = alpha @ wps^T  (fp32)
    {
        dim3 g(DD / GBN, BT_TOTAL / GBM);
        gemm_abT<<<g, 256, 0, stream>>>(alpha, NSY, wps, NSY, nullptr, out, DD, NSY);
    }
}

// Round 8
// 1138.068 us; speedup vs baseline: 1.9269x; 1.1358x over previous
//
#include <hip/hip_runtime.h>
#include <math.h>

#define BT_TOTAL 4096
#define DD 768
#define TWOD 1536
#define M_MEM 8
#define NHID 16
#define NSY 512
#define K_ITER 8

typedef unsigned short u16;
typedef __attribute__((ext_vector_type(8))) __bf16 bf16x8;
typedef __attribute__((ext_vector_type(4))) float f32x4;

__device__ __forceinline__ float sigmoidf_(float x) {
    return 1.0f / (1.0f + __expf(-x));
}

__device__ __forceinline__ u16 f2bf(float f) {
    unsigned int u = __float_as_uint(f);
    unsigned int r = (u + 0x7FFFu + ((u >> 16) & 1u)) >> 16;
    return (u16)r;
}
__device__ __forceinline__ float bf2f(u16 h) {
    return __uint_as_float(((unsigned int)h) << 16);
}

__device__ __forceinline__ void gload_lds16(const void* g, void* l) {
    __builtin_amdgcn_global_load_lds(
        (const __attribute__((address_space(1))) unsigned int*)g,
        (__attribute__((address_space(3))) unsigned int*)l,
        16, 0, 0);
}

// ---------------------------------------------------------------------------
// init: state hi/lo = split(start_state); alpha = 0
// ---------------------------------------------------------------------------
__global__ __launch_bounds__(256)
void init_kernel(u16* __restrict__ shi, u16* __restrict__ slo,
                 float* __restrict__ alpha, const float* __restrict__ start_state) {
    int idx = blockIdx.x * 256 + threadIdx.x;
    const int nstate = BT_TOTAL * DD;
    if (idx < nstate) {
        float a = start_state[idx % DD];
        u16 h = f2bf(a);
        shi[idx] = h;
        slo[idx] = f2bf(a - bf2f(h));
    } else {
        int a = idx - nstate;
        if (a < BT_TOTAL * NSY) alpha[a] = 0.0f;
    }
}

// ---------------------------------------------------------------------------
// split W_syn halves: wx = W[:, :768], ws = W[:, 768:]  (each 1536x768)
// ---------------------------------------------------------------------------
__global__ __launch_bounds__(256)
void split_w_kernel(const float* __restrict__ W,
                    u16* __restrict__ wxhi, u16* __restrict__ wxlo,
                    u16* __restrict__ wshi, u16* __restrict__ wslo) {
    int idx = blockIdx.x * 256 + threadIdx.x;   // < 1536*768
    int j = idx / DD, k = idx % DD;
    float a = W[(size_t)j * TWOD + k];
    float b = W[(size_t)j * TWOD + DD + k];
    u16 ha = f2bf(a); wxhi[idx] = ha; wxlo[idx] = f2bf(a - bf2f(ha));
    u16 hb = f2bf(b); wshi[idx] = hb; wslo[idx] = f2bf(b - bf2f(hb));
}

// ---------------------------------------------------------------------------
// split x -> xhi, xlo
// ---------------------------------------------------------------------------
__global__ __launch_bounds__(256)
void split_x_kernel(const float* __restrict__ x,
                    u16* __restrict__ xhi, u16* __restrict__ xlo) {
    int idx = blockIdx.x * 256 + threadIdx.x;   // < 4096*768
    float a = x[idx];
    u16 h = f2bf(a);
    xhi[idx] = h;
    xlo[idx] = f2bf(a - bf2f(h));
}

// ---------------------------------------------------------------------------
// wps[d][s] = W_proj[d][s] * rsqrt(beta[s]), written as bf16 hi/lo split
// ---------------------------------------------------------------------------
__global__ __launch_bounds__(256)
void scale_wproj_kernel(const float* __restrict__ wproj,
                        const float* __restrict__ decay,
                        u16* __restrict__ wpshi, u16* __restrict__ wpslo) {
    int idx = blockIdx.x * 256 + threadIdx.x;   // < 768*512
    int s = idx & (NSY - 1);
    float dcl = fminf(fmaxf(decay[s], 0.0f), 15.0f);
    float r = __expf(-dcl);
    float beta = 1.0f, rp = r;
    #pragma unroll
    for (int i = 1; i < K_ITER; ++i) { beta += rp; rp *= r; }
    float w = wproj[idx] * rsqrtf(beta);
    u16 h = f2bf(w);
    wpshi[idx] = h;
    wpslo[idx] = f2bf(w - bf2f(h));
}

// ---------------------------------------------------------------------------
// split alpha -> ahi, alo (for MFMA projection)
// ---------------------------------------------------------------------------
__global__ __launch_bounds__(256)
void split_alpha_kernel(const float* __restrict__ alpha,
                        u16* __restrict__ ahi, u16* __restrict__ alo) {
    int idx = blockIdx.x * 256 + threadIdx.x;   // < 4096*512
    float a = alpha[idx];
    u16 h = f2bf(a);
    ahi[idx] = h;
    alo[idx] = f2bf(a - bf2f(h));
}

// ---------------------------------------------------------------------------
// Split-bf16 MFMA GEMM: C(M x N) = (Ahi+Alo) @ (Bhi+Blo)^T + optional C0.
// A: M x Kdim (lda=Kdim), B: N x Kdim. 128x128 tile, BK=64, 4 waves,
// 16x16x32 bf16 MFMA, 3-term split. XOR-swizzled LDS, pre-swizzled global
// source (rule #21), global_load_lds width 16. Kdim multiple of 64.
// ---------------------------------------------------------------------------
#define TM 128
#define TN 128
#define TK 64

__global__ __launch_bounds__(256)
void gemm_mfma_split(const u16* __restrict__ Ahi, const u16* __restrict__ Alo,
                     const u16* __restrict__ Bhi, const u16* __restrict__ Blo,
                     const float* __restrict__ C0,
                     float* __restrict__ C, int ldc, int ldab, int Kdim) {
    __shared__ u16 sAh[TM * TK];
    __shared__ u16 sAl[TM * TK];
    __shared__ u16 sBh[TN * TK];
    __shared__ u16 sBl[TN * TK];
    const int tid  = threadIdx.x;
    const int w    = tid >> 6;
    const int lane = tid & 63;
    const int row0 = blockIdx.y * TM;
    const int col0 = blockIdx.x * TN;
    const int wr = (w >> 1) * 64;
    const int wc = (w & 1) * 64;

    const f32x4 zero = {0.f, 0.f, 0.f, 0.f};
    f32x4 acc[4][4];
    #pragma unroll
    for (int i = 0; i < 4; ++i)
        #pragma unroll
        for (int j = 0; j < 4; ++j) acc[i][j] = zero;

    const int lr = lane >> 3;
    const int ls = lane & 7;

    for (int kt = 0; kt < Kdim; kt += TK) {
        __syncthreads();
        #pragma unroll
        for (int g = 0; g < 4; ++g) {
            int r  = w * 32 + g * 8 + lr;
            int ss = ls ^ (r & 7);
            size_t goffA = (size_t)(row0 + r) * ldab + kt + ss * 8;
            size_t goffB = (size_t)(col0 + r) * ldab + kt + ss * 8;
            int lo = (w * 32 + g * 8) * TK;
            gload_lds16(Ahi + goffA, &sAh[lo]);
            gload_lds16(Alo + goffA, &sAl[lo]);
            gload_lds16(Bhi + goffB, &sBh[lo]);
            gload_lds16(Blo + goffB, &sBl[lo]);
        }
        __syncthreads();
        #pragma unroll
        for (int ks = 0; ks < 2; ++ks) {
            bf16x8 ah[4], al[4], bh[4], bl[4];
            #pragma unroll
            for (int f = 0; f < 4; ++f) {
                int ra = wr + f * 16 + (lane & 15);
                int sa = (ks * 4 + (lane >> 4)) ^ (ra & 7);
                ah[f] = *(const bf16x8*)(const void*)(sAh + ra * TK + sa * 8);
                al[f] = *(const bf16x8*)(const void*)(sAl + ra * TK + sa * 8);
                int rb = wc + f * 16 + (lane & 15);
                int sb = (ks * 4 + (lane >> 4)) ^ (rb & 7);
                bh[f] = *(const bf16x8*)(const void*)(sBh + rb * TK + sb * 8);
                bl[f] = *(const bf16x8*)(const void*)(sBl + rb * TK + sb * 8);
            }
            #pragma unroll
            for (int i = 0; i < 4; ++i)
                #pragma unroll
                for (int j = 0; j < 4; ++j) {
                    acc[i][j] = __builtin_amdgcn_mfma_f32_16x16x32_bf16(ah[i], bh[j], acc[i][j], 0, 0, 0);
                    acc[i][j] = __builtin_amdgcn_mfma_f32_16x16x32_bf16(ah[i], bl[j], acc[i][j], 0, 0, 0);
                    acc[i][j] = __builtin_amdgcn_mfma_f32_16x16x32_bf16(al[i], bh[j], acc[i][j], 0, 0, 0);
                }
        }
    }

    // epilogue: C/D layout col=lane&15, row=(lane>>4)*4+q  [m89-verified]
    const int cc = lane & 15;
    const int rr = (lane >> 4) * 4;
    #pragma unroll
    for (int i = 0; i < 4; ++i) {
        #pragma unroll
        for (int j = 0; j < 4; ++j) {
            int gr = row0 + wr + i * 16 + rr;
            int gc = col0 + wc + j * 16 + cc;
            #pragma unroll
            for (int q = 0; q < 4; ++q) {
                size_t off = (size_t)(gr + q) * ldc + gc;
                float v = acc[i][j][q];
                if (C0) v += C0[off];
                C[off] = v;
            }
        }
    }
}

// ---------------------------------------------------------------------------
// GLU + LayerNorm, one wave per row. act row: 1536; out: ns_hist[k] row: 768
// ---------------------------------------------------------------------------
__global__ __launch_bounds__(256)
void glu_ln_kernel(const float* __restrict__ act,
                   const float* __restrict__ ln_g, const float* __restrict__ ln_b,
                   float* __restrict__ ns_out) {
    int wave = threadIdx.x >> 6;
    int lane = threadIdx.x & 63;
    int row = blockIdx.x * 4 + wave;
    const float* arow = act + (size_t)row * TWOD;
    float g[12];
    float s = 0.0f, ss = 0.0f;
    #pragma unroll
    for (int q = 0; q < 12; ++q) {
        int c = lane + q * 64;
        float a = arow[c];
        float b = arow[c + DD];
        float v = a * sigmoidf_(b);
        g[q] = v; s += v; ss += v * v;
    }
    #pragma unroll
    for (int off = 32; off; off >>= 1) {
        s  += __shfl_xor(s, off);
        ss += __shfl_xor(ss, off);
    }
    float mu  = s * (1.0f / 768.0f);
    float var = ss * (1.0f / 768.0f) - mu * mu;
    float rstd = rsqrtf(var + 1e-5f);
    float* orow = ns_out + (size_t)row * DD;
    #pragma unroll
    for (int q = 0; q < 12; ++q) {
        int c = lane + q * 64;
        orow[c] = (g[q] - mu) * rstd * ln_g[c] + ln_b[c];
    }
}

// ---------------------------------------------------------------------------
// NLM: per-neuron 2-layer GLU MLP. Restructured: o-outer loop hoists the 16
// layer-1 weights + w2 pair + biases into registers, reused across 4 rows;
// layer-2 accumulated on the fly (no h[] array). Same FMA sequence as before
// (bitwise-identical math), ~3.6x fewer ds_read issues.
// ---------------------------------------------------------------------------
#define NC 32
#define RT 32

__global__ __launch_bounds__(256)
void nlm_kernel(const float* __restrict__ ns_hist, const float* __restrict__ st,
                const float* __restrict__ w1, const float* __restrict__ b1,
                const float* __restrict__ w2, const float* __restrict__ b2,
                u16* __restrict__ shi, u16* __restrict__ slo, int k) {
    __shared__ float w1s[M_MEM][32][NC];
    __shared__ float w2s[NHID][2][NC];
    __shared__ float b1s[NC][33];
    __shared__ float b2s[NC][3];
    __shared__ float sts[NC][9];
    const int tid = threadIdx.x;
    const int n0 = blockIdx.x * NC;
    const int r0 = blockIdx.y * RT;

    for (int idx = tid; idx < M_MEM * 32 * NC; idx += 256) {
        int mo = idx / NC, nl = idx % NC;
        ((float*)w1s)[idx] = w1[(size_t)mo * DD + n0 + nl];
    }
    for (int idx = tid; idx < NHID * 2 * NC; idx += 256) {
        int mo = idx / NC, nl = idx % NC;
        ((float*)w2s)[idx] = w2[(size_t)mo * DD + n0 + nl];
    }
    for (int idx = tid; idx < NC * 32; idx += 256) {
        int nl = idx >> 5, o = idx & 31;
        b1s[nl][o] = b1[(size_t)(n0 + nl) * 32 + o];
    }
    if (tid < NC * 2) { int nl = tid >> 1, o = tid & 1; b2s[nl][o] = b2[(size_t)(n0 + nl) * 2 + o]; }
    if (tid < NC * 8) { int nl = tid >> 3, m = tid & 7; sts[nl][m] = st[(size_t)(n0 + nl) * 8 + m]; }
    __syncthreads();

    const int nl = tid & (NC - 1);
    const int n = n0 + nl;
    const int rbase = r0 + (tid >> 5);

    // gather trace windows for 4 rows
    float t[4][M_MEM];
    #pragma unroll
    for (int ri = 0; ri < 4; ++ri) {
        int row = rbase + ri * 8;
        #pragma unroll
        for (int m = 0; m < M_MEM; ++m) {
            if (m < 7 - k)
                t[ri][m] = sts[nl][m + k + 1];
            else
                t[ri][m] = ns_hist[(size_t)(m - 7 + k) * (BT_TOTAL * DD) + (size_t)row * DD + n];
        }
    }

    float p0[4], p1[4];
    #pragma unroll
    for (int ri = 0; ri < 4; ++ri) { p0[ri] = b2s[nl][0]; p1[ri] = b2s[nl][1]; }

    #pragma unroll
    for (int o = 0; o < NHID; ++o) {
        float wa[M_MEM], wb[M_MEM];
        #pragma unroll
        for (int m = 0; m < M_MEM; ++m) {
            wa[m] = w1s[m][o][nl];
            wb[m] = w1s[m][o + 16][nl];
        }
        float w20 = w2s[o][0][nl], w21 = w2s[o][1][nl];
        float ba = b1s[nl][o], bb = b1s[nl][o + 16];
        #pragma unroll
        for (int ri = 0; ri < 4; ++ri) {
            float pa = ba, pb = bb;
            #pragma unroll
            for (int m = 0; m < M_MEM; ++m) {
                pa = fmaf(t[ri][m], wa[m], pa);
                pb = fmaf(t[ri][m], wb[m], pb);
            }
            float h = pa * sigmoidf_(pb);
            p0[ri] = fmaf(h, w20, p0[ri]);
            p1[ri] = fmaf(h, w21, p1[ri]);
        }
    }

    #pragma unroll
    for (int ri = 0; ri < 4; ++ri) {
        int row = rbase + ri * 8;
        float v = p0[ri] * sigmoidf_(p1[ri]);
        size_t off = (size_t)row * DD + n;
        u16 hv = f2bf(v);
        shi[off] = hv;
        slo[off] = f2bf(v - bf2f(hv));
    }
}

// ---------------------------------------------------------------------------
// pp + alpha update. One wave per row. State reconstructed from hi+lo.
// ---------------------------------------------------------------------------
__global__ __launch_bounds__(256)
void pp_kernel(const u16* __restrict__ shi, const u16* __restrict__ slo,
               const float* __restrict__ decay,
               const int* __restrict__ sl, const int* __restrict__ sr,
               float* __restrict__ alpha) {
    __shared__ float srow[4][DD];
    int wave = threadIdx.x >> 6, lane = threadIdx.x & 63;
    int row = blockIdx.x * 4 + wave;
    size_t base = (size_t)row * DD;
    #pragma unroll
    for (int q = 0; q < 12; ++q) {
        int c = lane + q * 64;
        srow[wave][c] = bf2f(shi[base + c]) + bf2f(slo[base + c]);
    }
    __syncthreads();
    float* arow = alpha + (size_t)row * NSY;
    #pragma unroll
    for (int q = 0; q < 8; ++q) {
        int s = lane + q * 64;
        float dcl = fminf(fmaxf(decay[s], 0.0f), 15.0f);
        float r = __expf(-dcl);
        float pp = srow[wave][sl[s]] * srow[wave][sr[s]];
        arow[s] = r * arow[s] + pp;
    }
}

// ---------------------------------------------------------------------------
extern "C" void kernel_launch(void* const* d_in, const int* in_sizes, int n_in,
                              void* d_out, int out_size, void* d_ws, size_t ws_size,
                              hipStream_t stream) {
    const float* x        = (const float*)d_in[0];
    const float* W_syn    = (const float*)d_in[1];
    const float* ln_g     = (const float*)d_in[2];
    const float* ln_b     = (const float*)d_in[3];
    const float* w1       = (const float*)d_in[4];
    const float* b1       = (const float*)d_in[5];
    const float* w2       = (const float*)d_in[6];
    const float* b2       = (const float*)d_in[7];
    const float* start_st = (const float*)d_in[8];
    const float* start_tr = (const float*)d_in[9];
    const float* decay    = (const float*)d_in[10];
    const float* W_proj   = (const float*)d_in[11];
    const int*   sl       = (const int*)d_in[12];
    const int*   sr       = (const int*)d_in[13];
    float* out = (float*)d_out;

    // fp32 region
    float* ws    = (float*)d_ws;
    float* xpre  = ws;                                     // 4096*1536
    float* act   = xpre  + (size_t)BT_TOTAL * TWOD;        // 4096*1536
    float* nsh   = act   + (size_t)BT_TOTAL * TWOD;        // 8*4096*768
    float* alpha = nsh   + (size_t)K_ITER * BT_TOTAL * DD; // 4096*512
    // u16 region (after floats; all offsets 16B-aligned)
    u16* u16base = (u16*)(alpha + (size_t)BT_TOTAL * NSY);
    u16* xhi   = u16base;                                  // 4096*768
    u16* xlo   = xhi   + (size_t)BT_TOTAL * DD;
    u16* shi   = xlo   + (size_t)BT_TOTAL * DD;
    u16* slo   = shi   + (size_t)BT_TOTAL * DD;
    u16* wxhi  = slo   + (size_t)BT_TOTAL * DD;            // 1536*768
    u16* wxlo  = wxhi  + (size_t)TWOD * DD;
    u16* wshi  = wxlo  + (size_t)TWOD * DD;
    u16* wslo  = wshi  + (size_t)TWOD * DD;
    u16* wpshi = wslo  + (size_t)TWOD * DD;                // 768*512
    u16* wpslo = wpshi + (size_t)DD * NSY;
    u16* ahi   = wpslo + (size_t)DD * NSY;                 // 4096*512
    u16* alo   = ahi   + (size_t)BT_TOTAL * NSY;

    {
        int total = BT_TOTAL * (DD + NSY);
        init_kernel<<<(total + 255) / 256, 256, 0, stream>>>(shi, slo, alpha, start_st);
    }
    split_w_kernel<<<(TWOD * DD) / 256, 256, 0, stream>>>(W_syn, wxhi, wxlo, wshi, wslo);
    split_x_kernel<<<(BT_TOTAL * DD) / 256, 256, 0, stream>>>(x, xhi, xlo);
    scale_wproj_kernel<<<(DD * NSY) / 256, 256, 0, stream>>>(W_proj, decay, wpshi, wpslo);

    // xpre = x @ W_x^T  (split-bf16 MFMA)
    {
        dim3 g(TWOD / TN, BT_TOTAL / TM);
        gemm_mfma_split<<<g, 256, 0, stream>>>(xhi, xlo, wxhi, wxlo, nullptr, xpre, TWOD, DD, DD);
    }

    for (int k = 0; k < K_ITER; ++k) {
        dim3 g(TWOD / TN, BT_TOTAL / TM);
        gemm_mfma_split<<<g, 256, 0, stream>>>(shi, slo, wshi, wslo, xpre, act, TWOD, DD, DD);
        glu_ln_kernel<<<BT_TOTAL / 4, 256, 0, stream>>>(act, ln_g, ln_b,
                                                        nsh + (size_t)k * BT_TOTAL * DD);
        dim3 gn(DD / NC, BT_TOTAL / RT);
        nlm_kernel<<<gn, 256, 0, stream>>>(nsh, start_tr, w1, b1, w2, b2, shi, slo, k);
        pp_kernel<<<BT_TOTAL / 4, 256, 0, stream>>>(shi, slo, decay, sl, sr, alpha);
    }

    // out = alpha @ wps^T  (split-bf16 MFMA, K=512)
    split_alpha_kernel<<<(BT_TOTAL * NSY) / 256, 256, 0, stream>>>(alpha, ahi, alo);
    {
        dim3 g(DD / TN, BT_TOTAL / TM);
        gemm_mfma_split<<<g, 256, 0, stream>>>(ahi, alo, wpshi, wpslo, nullptr, out, DD, NSY, NSY);
    }
}

// Round 9
// 1094.879 us; speedup vs baseline: 2.0029x; 1.0394x over previous
//
#include <hip/hip_runtime.h>
#include <math.h>

#define BT_TOTAL 4096
#define DD 768
#define TWOD 1536
#define M_MEM 8
#define NHID 16
#define NSY 512
#define K_ITER 8

typedef unsigned short u16;
typedef __attribute__((ext_vector_type(8))) __bf16 bf16x8;
typedef __attribute__((ext_vector_type(4))) float f32x4;

__device__ __forceinline__ float sigmoidf_(float x) {
    return 1.0f / (1.0f + __expf(-x));
}

__device__ __forceinline__ u16 f2bf(float f) {
    unsigned int u = __float_as_uint(f);
    unsigned int r = (u + 0x7FFFu + ((u >> 16) & 1u)) >> 16;
    return (u16)r;
}
__device__ __forceinline__ float bf2f(u16 h) {
    return __uint_as_float(((unsigned int)h) << 16);
}

__device__ __forceinline__ void gload_lds16(const void* g, void* l) {
    __builtin_amdgcn_global_load_lds(
        (const __attribute__((address_space(1))) unsigned int*)g,
        (__attribute__((address_space(3))) unsigned int*)l,
        16, 0, 0);
}

// ---------------------------------------------------------------------------
// init: state hi/lo = split(start_state); alpha = 0
// ---------------------------------------------------------------------------
__global__ __launch_bounds__(256)
void init_kernel(u16* __restrict__ shi, u16* __restrict__ slo,
                 float* __restrict__ alpha, const float* __restrict__ start_state) {
    int idx = blockIdx.x * 256 + threadIdx.x;
    const int nstate = BT_TOTAL * DD;
    if (idx < nstate) {
        float a = start_state[idx % DD];
        u16 h = f2bf(a);
        shi[idx] = h;
        slo[idx] = f2bf(a - bf2f(h));
    } else {
        int a = idx - nstate;
        if (a < BT_TOTAL * NSY) alpha[a] = 0.0f;
    }
}

// ---------------------------------------------------------------------------
// split W_syn halves: wx = W[:, :768], ws = W[:, 768:]  (each 1536x768)
// ---------------------------------------------------------------------------
__global__ __launch_bounds__(256)
void split_w_kernel(const float* __restrict__ W,
                    u16* __restrict__ wxhi, u16* __restrict__ wxlo,
                    u16* __restrict__ wshi, u16* __restrict__ wslo) {
    int idx = blockIdx.x * 256 + threadIdx.x;   // < 1536*768
    int j = idx / DD, k = idx % DD;
    float a = W[(size_t)j * TWOD + k];
    float b = W[(size_t)j * TWOD + DD + k];
    u16 ha = f2bf(a); wxhi[idx] = ha; wxlo[idx] = f2bf(a - bf2f(ha));
    u16 hb = f2bf(b); wshi[idx] = hb; wslo[idx] = f2bf(b - bf2f(hb));
}

// ---------------------------------------------------------------------------
// split x -> xhi, xlo
// ---------------------------------------------------------------------------
__global__ __launch_bounds__(256)
void split_x_kernel(const float* __restrict__ x,
                    u16* __restrict__ xhi, u16* __restrict__ xlo) {
    int idx = blockIdx.x * 256 + threadIdx.x;   // < 4096*768
    float a = x[idx];
    u16 h = f2bf(a);
    xhi[idx] = h;
    xlo[idx] = f2bf(a - bf2f(h));
}

// ---------------------------------------------------------------------------
// wps[d][s] = W_proj[d][s] * rsqrt(beta[s]), written as bf16 hi/lo split
// ---------------------------------------------------------------------------
__global__ __launch_bounds__(256)
void scale_wproj_kernel(const float* __restrict__ wproj,
                        const float* __restrict__ decay,
                        u16* __restrict__ wpshi, u16* __restrict__ wpslo) {
    int idx = blockIdx.x * 256 + threadIdx.x;   // < 768*512
    int s = idx & (NSY - 1);
    float dcl = fminf(fmaxf(decay[s], 0.0f), 15.0f);
    float r = __expf(-dcl);
    float beta = 1.0f, rp = r;
    #pragma unroll
    for (int i = 1; i < K_ITER; ++i) { beta += rp; rp *= r; }
    float w = wproj[idx] * rsqrtf(beta);
    u16 h = f2bf(w);
    wpshi[idx] = h;
    wpslo[idx] = f2bf(w - bf2f(h));
}

// ---------------------------------------------------------------------------
// split alpha -> ahi, alo (for MFMA projection)
// ---------------------------------------------------------------------------
__global__ __launch_bounds__(256)
void split_alpha_kernel(const float* __restrict__ alpha,
                        u16* __restrict__ ahi, u16* __restrict__ alo) {
    int idx = blockIdx.x * 256 + threadIdx.x;   // < 4096*512
    float a = alpha[idx];
    u16 h = f2bf(a);
    ahi[idx] = h;
    alo[idx] = f2bf(a - bf2f(h));
}

// ---------------------------------------------------------------------------
// Split-bf16 MFMA GEMM: C(M x N) = (Ahi+Alo) @ (Bhi+Blo)^T + optional C0.
// A: M x Kdim (lda=Kdim), B: N x Kdim. 128x128 tile, BK=64, 4 waves,
// 16x16x32 bf16 MFMA, 3-term split. XOR-swizzled LDS, pre-swizzled global
// source (rule #21), global_load_lds width 16. Kdim multiple of 64.
// ---------------------------------------------------------------------------
#define TM 128
#define TN 128
#define TK 64

__global__ __launch_bounds__(256)
void gemm_mfma_split(const u16* __restrict__ Ahi, const u16* __restrict__ Alo,
                     const u16* __restrict__ Bhi, const u16* __restrict__ Blo,
                     const float* __restrict__ C0,
                     float* __restrict__ C, int ldc, int ldab, int Kdim) {
    __shared__ u16 sAh[TM * TK];
    __shared__ u16 sAl[TM * TK];
    __shared__ u16 sBh[TN * TK];
    __shared__ u16 sBl[TN * TK];
    const int tid  = threadIdx.x;
    const int w    = tid >> 6;
    const int lane = tid & 63;
    const int row0 = blockIdx.y * TM;
    const int col0 = blockIdx.x * TN;
    const int wr = (w >> 1) * 64;
    const int wc = (w & 1) * 64;

    const f32x4 zero = {0.f, 0.f, 0.f, 0.f};
    f32x4 acc[4][4];
    #pragma unroll
    for (int i = 0; i < 4; ++i)
        #pragma unroll
        for (int j = 0; j < 4; ++j) acc[i][j] = zero;

    const int lr = lane >> 3;
    const int ls = lane & 7;

    for (int kt = 0; kt < Kdim; kt += TK) {
        __syncthreads();
        #pragma unroll
        for (int g = 0; g < 4; ++g) {
            int r  = w * 32 + g * 8 + lr;
            int ss = ls ^ (r & 7);
            size_t goffA = (size_t)(row0 + r) * ldab + kt + ss * 8;
            size_t goffB = (size_t)(col0 + r) * ldab + kt + ss * 8;
            int lo = (w * 32 + g * 8) * TK;
            gload_lds16(Ahi + goffA, &sAh[lo]);
            gload_lds16(Alo + goffA, &sAl[lo]);
            gload_lds16(Bhi + goffB, &sBh[lo]);
            gload_lds16(Blo + goffB, &sBl[lo]);
        }
        __syncthreads();
        #pragma unroll
        for (int ks = 0; ks < 2; ++ks) {
            bf16x8 ah[4], al[4], bh[4], bl[4];
            #pragma unroll
            for (int f = 0; f < 4; ++f) {
                int ra = wr + f * 16 + (lane & 15);
                int sa = (ks * 4 + (lane >> 4)) ^ (ra & 7);
                ah[f] = *(const bf16x8*)(const void*)(sAh + ra * TK + sa * 8);
                al[f] = *(const bf16x8*)(const void*)(sAl + ra * TK + sa * 8);
                int rb = wc + f * 16 + (lane & 15);
                int sb = (ks * 4 + (lane >> 4)) ^ (rb & 7);
                bh[f] = *(const bf16x8*)(const void*)(sBh + rb * TK + sb * 8);
                bl[f] = *(const bf16x8*)(const void*)(sBl + rb * TK + sb * 8);
            }
            #pragma unroll
            for (int i = 0; i < 4; ++i)
                #pragma unroll
                for (int j = 0; j < 4; ++j) {
                    acc[i][j] = __builtin_amdgcn_mfma_f32_16x16x32_bf16(ah[i], bh[j], acc[i][j], 0, 0, 0);
                    acc[i][j] = __builtin_amdgcn_mfma_f32_16x16x32_bf16(ah[i], bl[j], acc[i][j], 0, 0, 0);
                    acc[i][j] = __builtin_amdgcn_mfma_f32_16x16x32_bf16(al[i], bh[j], acc[i][j], 0, 0, 0);
                }
        }
    }

    // epilogue: C/D layout col=lane&15, row=(lane>>4)*4+q  [m89-verified]
    const int cc = lane & 15;
    const int rr = (lane >> 4) * 4;
    #pragma unroll
    for (int i = 0; i < 4; ++i) {
        #pragma unroll
        for (int j = 0; j < 4; ++j) {
            int gr = row0 + wr + i * 16 + rr;
            int gc = col0 + wc + j * 16 + cc;
            #pragma unroll
            for (int q = 0; q < 4; ++q) {
                size_t off = (size_t)(gr + q) * ldc + gc;
                float v = acc[i][j][q];
                if (C0) v += C0[off];
                C[off] = v;
            }
        }
    }
}

// ---------------------------------------------------------------------------
// GLU + LayerNorm, one wave per row. act row: 1536; out: ns_hist[k] row: 768
// ---------------------------------------------------------------------------
__global__ __launch_bounds__(256)
void glu_ln_kernel(const float* __restrict__ act,
                   const float* __restrict__ ln_g, const float* __restrict__ ln_b,
                   float* __restrict__ ns_out) {
    int wave = threadIdx.x >> 6;
    int lane = threadIdx.x & 63;
    int row = blockIdx.x * 4 + wave;
    const float* arow = act + (size_t)row * TWOD;
    float g[12];
    float s = 0.0f, ss = 0.0f;
    #pragma unroll
    for (int q = 0; q < 12; ++q) {
        int c = lane + q * 64;
        float a = arow[c];
        float b = arow[c + DD];
        float v = a * sigmoidf_(b);
        g[q] = v; s += v; ss += v * v;
    }
    #pragma unroll
    for (int off = 32; off; off >>= 1) {
        s  += __shfl_xor(s, off);
        ss += __shfl_xor(ss, off);
    }
    float mu  = s * (1.0f / 768.0f);
    float var = ss * (1.0f / 768.0f) - mu * mu;
    float rstd = rsqrtf(var + 1e-5f);
    float* orow = ns_out + (size_t)row * DD;
    #pragma unroll
    for (int q = 0; q < 12; ++q) {
        int c = lane + q * 64;
        orow[c] = (g[q] - mu) * rstd * ln_g[c] + ln_b[c];
    }
}

// ---------------------------------------------------------------------------
// NLM: per-neuron 2-layer GLU MLP. o-outer register-hoisted weights (r6 WIN),
// NC=16/RT=64 to cut LDS 43KB->21KB: 3 -> 7 blocks/CU occupancy (r8 theory:
// issue-limited at 28% occupancy). Same per-thread FMA sequence.
// ---------------------------------------------------------------------------
#define NC 16
#define RT 64

__global__ __launch_bounds__(256)
void nlm_kernel(const float* __restrict__ ns_hist, const float* __restrict__ st,
                const float* __restrict__ w1, const float* __restrict__ b1,
                const float* __restrict__ w2, const float* __restrict__ b2,
                u16* __restrict__ shi, u16* __restrict__ slo, int k) {
    __shared__ float w1s[M_MEM][32][NC];   // 16 KB
    __shared__ float w2s[NHID][2][NC];     // 2 KB
    __shared__ float b1s[NC][33];
    __shared__ float b2s[NC][3];
    __shared__ float sts[NC][9];
    const int tid = threadIdx.x;
    const int n0 = blockIdx.x * NC;
    const int r0 = blockIdx.y * RT;

    for (int idx = tid; idx < M_MEM * 32 * NC; idx += 256) {
        int mo = idx / NC, nl = idx % NC;
        ((float*)w1s)[idx] = w1[(size_t)mo * DD + n0 + nl];
    }
    for (int idx = tid; idx < NHID * 2 * NC; idx += 256) {
        int mo = idx / NC, nl = idx % NC;
        ((float*)w2s)[idx] = w2[(size_t)mo * DD + n0 + nl];
    }
    for (int idx = tid; idx < NC * 32; idx += 256) {
        int nl = idx >> 5, o = idx & 31;
        b1s[nl][o] = b1[(size_t)(n0 + nl) * 32 + o];
    }
    if (tid < NC * 2) { int nl = tid >> 1, o = tid & 1; b2s[nl][o] = b2[(size_t)(n0 + nl) * 2 + o]; }
    if (tid < NC * 8) { int nl = tid >> 3, m = tid & 7; sts[nl][m] = st[(size_t)(n0 + nl) * 8 + m]; }
    __syncthreads();

    const int nl = tid & (NC - 1);
    const int n = n0 + nl;
    const int rbase = r0 + (tid >> 4);   // 16 row groups

    // gather trace windows for 4 rows (stride 16)
    float t[4][M_MEM];
    #pragma unroll
    for (int ri = 0; ri < 4; ++ri) {
        int row = rbase + ri * 16;
        #pragma unroll
        for (int m = 0; m < M_MEM; ++m) {
            if (m < 7 - k)
                t[ri][m] = sts[nl][m + k + 1];
            else
                t[ri][m] = ns_hist[(size_t)(m - 7 + k) * (BT_TOTAL * DD) + (size_t)row * DD + n];
        }
    }

    float p0[4], p1[4];
    #pragma unroll
    for (int ri = 0; ri < 4; ++ri) { p0[ri] = b2s[nl][0]; p1[ri] = b2s[nl][1]; }

    #pragma unroll
    for (int o = 0; o < NHID; ++o) {
        float wa[M_MEM], wb[M_MEM];
        #pragma unroll
        for (int m = 0; m < M_MEM; ++m) {
            wa[m] = w1s[m][o][nl];
            wb[m] = w1s[m][o + 16][nl];
        }
        float w20 = w2s[o][0][nl], w21 = w2s[o][1][nl];
        float ba = b1s[nl][o], bb = b1s[nl][o + 16];
        #pragma unroll
        for (int ri = 0; ri < 4; ++ri) {
            float pa = ba, pb = bb;
            #pragma unroll
            for (int m = 0; m < M_MEM; ++m) {
                pa = fmaf(t[ri][m], wa[m], pa);
                pb = fmaf(t[ri][m], wb[m], pb);
            }
            float h = pa * sigmoidf_(pb);
            p0[ri] = fmaf(h, w20, p0[ri]);
            p1[ri] = fmaf(h, w21, p1[ri]);
        }
    }

    #pragma unroll
    for (int ri = 0; ri < 4; ++ri) {
        int row = rbase + ri * 16;
        float v = p0[ri] * sigmoidf_(p1[ri]);
        size_t off = (size_t)row * DD + n;
        u16 hv = f2bf(v);
        shi[off] = hv;
        slo[off] = f2bf(v - bf2f(hv));
    }
}

// ---------------------------------------------------------------------------
// pp + alpha update. One wave per row. State reconstructed from hi+lo.
// ---------------------------------------------------------------------------
__global__ __launch_bounds__(256)
void pp_kernel(const u16* __restrict__ shi, const u16* __restrict__ slo,
               const float* __restrict__ decay,
               const int* __restrict__ sl, const int* __restrict__ sr,
               float* __restrict__ alpha) {
    __shared__ float srow[4][DD];
    int wave = threadIdx.x >> 6, lane = threadIdx.x & 63;
    int row = blockIdx.x * 4 + wave;
    size_t base = (size_t)row * DD;
    #pragma unroll
    for (int q = 0; q < 12; ++q) {
        int c = lane + q * 64;
        srow[wave][c] = bf2f(shi[base + c]) + bf2f(slo[base + c]);
    }
    __syncthreads();
    float* arow = alpha + (size_t)row * NSY;
    #pragma unroll
    for (int q = 0; q < 8; ++q) {
        int s = lane + q * 64;
        float dcl = fminf(fmaxf(decay[s], 0.0f), 15.0f);
        float r = __expf(-dcl);
        float pp = srow[wave][sl[s]] * srow[wave][sr[s]];
        arow[s] = r * arow[s] + pp;
    }
}

// ---------------------------------------------------------------------------
extern "C" void kernel_launch(void* const* d_in, const int* in_sizes, int n_in,
                              void* d_out, int out_size, void* d_ws, size_t ws_size,
                              hipStream_t stream) {
    const float* x        = (const float*)d_in[0];
    const float* W_syn    = (const float*)d_in[1];
    const float* ln_g     = (const float*)d_in[2];
    const float* ln_b     = (const float*)d_in[3];
    const float* w1       = (const float*)d_in[4];
    const float* b1       = (const float*)d_in[5];
    const float* w2       = (const float*)d_in[6];
    const float* b2       = (const float*)d_in[7];
    const float* start_st = (const float*)d_in[8];
    const float* start_tr = (const float*)d_in[9];
    const float* decay    = (const float*)d_in[10];
    const float* W_proj   = (const float*)d_in[11];
    const int*   sl       = (const int*)d_in[12];
    const int*   sr       = (const int*)d_in[13];
    float* out = (float*)d_out;

    // fp32 region
    float* ws    = (float*)d_ws;
    float* xpre  = ws;                                     // 4096*1536
    float* act   = xpre  + (size_t)BT_TOTAL * TWOD;        // 4096*1536
    float* nsh   = act   + (size_t)BT_TOTAL * TWOD;        // 8*4096*768
    float* alpha = nsh   + (size_t)K_ITER * BT_TOTAL * DD; // 4096*512
    // u16 region (after floats; all offsets 16B-aligned)
    u16* u16base = (u16*)(alpha + (size_t)BT_TOTAL * NSY);
    u16* xhi   = u16base;                                  // 4096*768
    u16* xlo   = xhi   + (size_t)BT_TOTAL * DD;
    u16* shi   = xlo   + (size_t)BT_TOTAL * DD;
    u16* slo   = shi   + (size_t)BT_TOTAL * DD;
    u16* wxhi  = slo   + (size_t)BT_TOTAL * DD;            // 1536*768
    u16* wxlo  = wxhi  + (size_t)TWOD * DD;
    u16* wshi  = wxlo  + (size_t)TWOD * DD;
    u16* wslo  = wshi  + (size_t)TWOD * DD;
    u16* wpshi = wslo  + (size_t)TWOD * DD;                // 768*512
    u16* wpslo = wpshi + (size_t)DD * NSY;
    u16* ahi   = wpslo + (size_t)DD * NSY;                 // 4096*512
    u16* alo   = ahi   + (size_t)BT_TOTAL * NSY;

    {
        int total = BT_TOTAL * (DD + NSY);
        init_kernel<<<(total + 255) / 256, 256, 0, stream>>>(shi, slo, alpha, start_st);
    }
    split_w_kernel<<<(TWOD * DD) / 256, 256, 0, stream>>>(W_syn, wxhi, wxlo, wshi, wslo);
    split_x_kernel<<<(BT_TOTAL * DD) / 256, 256, 0, stream>>>(x, xhi, xlo);
    scale_wproj_kernel<<<(DD * NSY) / 256, 256, 0, stream>>>(W_proj, decay, wpshi, wpslo);

    // xpre = x @ W_x^T  (split-bf16 MFMA)
    {
        dim3 g(TWOD / TN, BT_TOTAL / TM);
        gemm_mfma_split<<<g, 256, 0, stream>>>(xhi, xlo, wxhi, wxlo, nullptr, xpre, TWOD, DD, DD);
    }

    for (int k = 0; k < K_ITER; ++k) {
        dim3 g(TWOD / TN, BT_TOTAL / TM);
        gemm_mfma_split<<<g, 256, 0, stream>>>(shi, slo, wshi, wslo, xpre, act, TWOD, DD, DD);
        glu_ln_kernel<<<BT_TOTAL / 4, 256, 0, stream>>>(act, ln_g, ln_b,
                                                        nsh + (size_t)k * BT_TOTAL * DD);
        dim3 gn(DD / NC, BT_TOTAL / RT);
        nlm_kernel<<<gn, 256, 0, stream>>>(nsh, start_tr, w1, b1, w2, b2, shi, slo, k);
        pp_kernel<<<BT_TOTAL / 4, 256, 0, stream>>>(shi, slo, decay, sl, sr, alpha);
    }

    // out = alpha @ wps^T  (split-bf16 MFMA, K=512)
    split_alpha_kernel<<<(BT_TOTAL * NSY) / 256, 256, 0, stream>>>(alpha, ahi, alo);
    {
        dim3 g(DD / TN, BT_TOTAL / TM);
        gemm_mfma_split<<<g, 256, 0, stream>>>(ahi, alo, wpshi, wpslo, nullptr, out, DD, NSY, NSY);
    }
}